// Round 1
// baseline (240.405 us; speedup 1.0000x reference)
//
#include <hip/hip_runtime.h>
#include <math.h>

#define SS 512
#define BB 512
#define TT 64

__device__ __forceinline__ float bcast_lane0(float x) {
    return __int_as_float(__builtin_amdgcn_readfirstlane(__float_as_int(x)));
}

// Kernel A: blocks [0,B): forward chains; [B,2B): backward chains; [2B,3B): numerator.
// One wave (64 threads) per block. lane = tag index for chains, = time-slice for numerator.
__global__ __launch_bounds__(64) void crf_chains(
    const float* __restrict__ em,      // S,B,T
    const int*   __restrict__ tags,    // S,B (int32)
    const int*   __restrict__ mask,    // S,B (int32 0/1)
    const float* __restrict__ start_t, // T
    const float* __restrict__ end_t,   // T
    const float* __restrict__ trans,   // T,T
    float* __restrict__ alpha_mid,     // B,T
    float* __restrict__ beta_mid,      // B,T
    float* __restrict__ num_ws)        // B
{
    const int lane = threadIdx.x;
    const int bid  = blockIdx.x;
    __shared__ float lds[TT * 65];   // transpose staging (bwd) / p-broadcast buffer

    if (bid < BB) {
        // ---------------- forward chain: alpha_0 .. alpha_255 ----------------
        const int b = bid;
        // e[i] = exp(trans[i][lane])  (column of E held in registers)
        float e[TT];
        #pragma unroll
        for (int i = 0; i < TT; ++i)
            e[i] = __expf(trans[i * TT + lane]);

        float alpha = start_t[lane] + em[(size_t)b * TT + lane];

        // 2-deep prefetch pipeline for em / mask
        float emA = em[(size_t)1 * BB * TT + (size_t)b * TT + lane];
        float emB = em[(size_t)2 * BB * TT + (size_t)b * TT + lane];
        int   mkA = mask[1 * BB + b];
        int   mkB = mask[2 * BB + b];

        for (int s = 1; s <= 255; ++s) {
            int sp = s + 2; if (sp > 255) sp = 255;
            float emC = em[(size_t)sp * BB * TT + (size_t)b * TT + lane];
            int   mkC = mask[sp * BB + b];

            float off = bcast_lane0(alpha);
            float p   = __expf(alpha - off);
            lds[lane] = p;
            __syncthreads();

            float a0 = 0.f, a1 = 0.f, a2 = 0.f, a3 = 0.f;
            #pragma unroll
            for (int i = 0; i < 16; ++i) {
                float4 pv = *(const float4*)&lds[i * 4];
                a0 += pv.x * e[4 * i + 0];
                a1 += pv.y * e[4 * i + 1];
                a2 += pv.z * e[4 * i + 2];
                a3 += pv.w * e[4 * i + 3];
            }
            float acc = (a0 + a1) + (a2 + a3);
            float na  = emA + off + __logf(acc);
            alpha = mkA ? na : alpha;

            emA = emB; emB = emC; mkA = mkB; mkB = mkC;
            __syncthreads();   // lds reuse fence before next iteration's write
        }
        alpha_mid[(size_t)b * TT + lane] = alpha;

    } else if (bid < 2 * BB) {
        // ---------------- backward chain: beta_511 .. beta_255 ----------------
        const int b = bid - BB;
        // Need row lane of E: exp(trans[lane][j]). Stage via LDS transpose so the
        // global reads stay coalesced and LDS reads are conflict-free (pad 65).
        for (int k = 0; k < TT; ++k)
            lds[k * 65 + lane] = trans[k * TT + lane];
        __syncthreads();
        float e[TT];
        #pragma unroll
        for (int j = 0; j < TT; ++j)
            e[j] = __expf(lds[lane * 65 + j]);
        __syncthreads();

        float beta = end_t[lane];

        float emA = em[(size_t)511 * BB * TT + (size_t)b * TT + lane];
        float emB = em[(size_t)510 * BB * TT + (size_t)b * TT + lane];
        int   mkA = mask[511 * BB + b];
        int   mkB = mask[510 * BB + b];

        for (int s = 511; s >= 256; --s) {
            int sp = s - 2; if (sp < 256) sp = 256;
            float emC = em[(size_t)sp * BB * TT + (size_t)b * TT + lane];
            int   mkC = mask[sp * BB + b];

            float qa  = emA + beta;
            float off = bcast_lane0(qa);
            float q   = __expf(qa - off);
            lds[lane] = q;
            __syncthreads();

            float a0 = 0.f, a1 = 0.f, a2 = 0.f, a3 = 0.f;
            #pragma unroll
            for (int j = 0; j < 16; ++j) {
                float4 qv = *(const float4*)&lds[j * 4];
                a0 += qv.x * e[4 * j + 0];
                a1 += qv.y * e[4 * j + 1];
                a2 += qv.z * e[4 * j + 2];
                a3 += qv.w * e[4 * j + 3];
            }
            float acc = (a0 + a1) + (a2 + a3);
            float nb  = off + __logf(acc);
            beta = mkA ? nb : beta;

            emA = emB; emB = emC; mkA = mkB; mkB = mkC;
            __syncthreads();
        }
        beta_mid[(size_t)b * TT + lane] = beta;

    } else {
        // ---------------- numerator (tag-path score) ----------------
        const int b = bid - 2 * BB;
        float local = 0.f;
        int   mcnt  = 0;
        for (int s = lane; s < SS; s += 64) {
            int tag = tags[s * BB + b];
            int mk  = mask[s * BB + b];
            mcnt += mk;
            if (s == 0) {
                local += start_t[tag] + em[(size_t)b * TT + tag];
            } else if (mk) {
                int tp = tags[(s - 1) * BB + b];
                local += trans[tp * TT + tag] + em[(size_t)s * BB * TT + (size_t)b * TT + tag];
            }
        }
        #pragma unroll
        for (int d = 32; d > 0; d >>= 1) {
            local += __shfl_down(local, d, 64);
            mcnt  += __shfl_down(mcnt, d, 64);
        }
        if (lane == 0) {
            int last = tags[(mcnt - 1) * BB + b];
            num_ws[b] = local + end_t[last];
        }
    }
}

// Kernel B: combine alpha_mid + beta_mid -> denominator, llh mean -> out[0].
__global__ __launch_bounds__(512) void crf_combine(
    const float* __restrict__ alpha_mid,
    const float* __restrict__ beta_mid,
    const float* __restrict__ num_ws,
    float* __restrict__ out)
{
    const int b = threadIdx.x;       // 512 threads, one per batch element
    const float4* A  = (const float4*)(alpha_mid + (size_t)b * TT);
    const float4* Bt = (const float4*)(beta_mid  + (size_t)b * TT);

    float mx = -1e30f;
    #pragma unroll
    for (int k = 0; k < 16; ++k) {
        float4 a = A[k], c = Bt[k];
        mx = fmaxf(mx, fmaxf(fmaxf(a.x + c.x, a.y + c.y), fmaxf(a.z + c.z, a.w + c.w)));
    }
    float sum = 0.f;
    #pragma unroll
    for (int k = 0; k < 16; ++k) {
        float4 a = A[k], c = Bt[k];
        sum += __expf(a.x + c.x - mx) + __expf(a.y + c.y - mx)
             + __expf(a.z + c.z - mx) + __expf(a.w + c.w - mx);
    }
    float denom = mx + __logf(sum);
    float llh   = num_ws[b] - denom;

    // block reduction (8 waves)
    float wsum = llh;
    #pragma unroll
    for (int d = 32; d > 0; d >>= 1) wsum += __shfl_down(wsum, d, 64);
    __shared__ float red[8];
    if ((threadIdx.x & 63) == 0) red[threadIdx.x >> 6] = wsum;
    __syncthreads();
    if (threadIdx.x == 0) {
        float t = 0.f;
        #pragma unroll
        for (int w = 0; w < 8; ++w) t += red[w];
        out[0] = t / (float)BB;
    }
}

extern "C" void kernel_launch(void* const* d_in, const int* in_sizes, int n_in,
                              void* d_out, int out_size, void* d_ws, size_t ws_size,
                              hipStream_t stream) {
    const float* em    = (const float*)d_in[0];
    const int*   tags  = (const int*)d_in[1];
    const int*   mask  = (const int*)d_in[2];
    const float* st    = (const float*)d_in[3];
    const float* en    = (const float*)d_in[4];
    const float* tr    = (const float*)d_in[5];

    float* ws        = (float*)d_ws;
    float* alpha_mid = ws;                      // B*T floats
    float* beta_mid  = ws + (size_t)BB * TT;    // B*T floats
    float* num_ws    = ws + (size_t)2 * BB * TT; // B floats

    crf_chains<<<3 * BB, 64, 0, stream>>>(em, tags, mask, st, en, tr,
                                          alpha_mid, beta_mid, num_ws);
    crf_combine<<<1, 512, 0, stream>>>(alpha_mid, beta_mid, num_ws, (float*)d_out);
}

// Round 2
// 190.990 us; speedup vs baseline: 1.2587x; 1.2587x over previous
//
#include <hip/hip_runtime.h>
#include <math.h>

#define SS 512
#define BB 512
#define TT 64
#define GRP 8

__device__ __forceinline__ float bl0(float x) {
    return __int_as_float(__builtin_amdgcn_readfirstlane(__float_as_int(x)));
}

// blocks [0,B): forward chains; [B,2B): backward chains; [2B,3B): numerator.
// One wave per block; NO barriers inside the recursion (single-wave block,
// DS ops are in-order per wave; p is double-buffered by step parity).
__global__ __launch_bounds__(64) void crf_chains(
    const float* __restrict__ em,      // S,B,T
    const int*   __restrict__ tags,    // S,B (int32 via harness)
    const int*   __restrict__ mask,    // S,B (int32 0/1)
    const float* __restrict__ start_t, // T
    const float* __restrict__ end_t,   // T
    const float* __restrict__ trans,   // T,T
    float* __restrict__ alpha_mid,     // B,T
    float* __restrict__ beta_mid,      // B,T
    float* __restrict__ num_ws)        // B
{
    const int lane = threadIdx.x;
    const int bid  = blockIdx.x;
    __shared__ float lds[TT * 65];     // [0..127]: p double-buffer; also bwd transpose staging

    if (bid < BB) {
        // ---------------- forward: alpha_0 .. alpha_255 ----------------
        const int b = bid;
        const float* embase = em + (size_t)b * TT + lane;
        const int*   mkbase = mask + b;

        float e[TT];                    // e[i] = exp(trans[i][lane]) : column of E
        #pragma unroll
        for (int i = 0; i < TT; ++i)
            e[i] = __expf(trans[i * TT + lane]);

        float alpha = start_t[lane] + embase[0];

        float em0[GRP], em1[GRP];
        int   mk0[GRP], mk1[GRP];

        auto LOADF = [&](float* eb, int* mb, int g) {
            const int sb = 1 + g * GRP;                  // prefetch overrun stays < 512
            #pragma unroll
            for (int k = 0; k < GRP; ++k) {
                eb[k] = embase[(size_t)(sb + k) * BB * TT];
                mb[k] = mkbase[(sb + k) * BB];
            }
        };
        auto STEPSF = [&](const float* eb, const int* mb, bool lastg) {
            #pragma unroll
            for (int k = 0; k < GRP; ++k) {
                const int par = (k & 1) * TT;
                float off = bl0(alpha);
                float p   = __expf(alpha - off);
                lds[par + lane] = p;
                float a0 = 0.f, a1 = 0.f, a2 = 0.f, a3 = 0.f;
                #pragma unroll
                for (int i = 0; i < 16; ++i) {
                    float4 pv = *(const float4*)&lds[par + i * 4];
                    a0 += pv.x * e[4 * i + 0];
                    a1 += pv.y * e[4 * i + 1];
                    a2 += pv.z * e[4 * i + 2];
                    a3 += pv.w * e[4 * i + 3];
                }
                float acc = (a0 + a1) + (a2 + a3);
                float na  = eb[k] + off + __logf(acc);
                int mk = mb[k];
                if (k == GRP - 1) mk = lastg ? 0 : mk;   // virtual masked step s=256
                alpha = mk ? na : alpha;
            }
        };

        LOADF(em0, mk0, 0);
        LOADF(em1, mk1, 1);
        for (int gg = 0; gg < 32; gg += 2) {
            STEPSF(em0, mk0, false);          // group gg (even, never 31)
            LOADF(em0, mk0, gg + 2);
            STEPSF(em1, mk1, gg + 1 == 31);   // group gg+1
            LOADF(em1, mk1, gg + 3);
        }
        alpha_mid[(size_t)b * TT + lane] = alpha;

    } else if (bid < 2 * BB) {
        // ---------------- backward: beta_511 .. beta_255 ----------------
        const int b = bid - BB;
        const float* embase = em + (size_t)b * TT + lane;
        const int*   mkbase = mask + b;

        // row lane of E via LDS transpose (coalesced global, conflict-free LDS)
        for (int k = 0; k < TT; ++k)
            lds[k * 65 + lane] = trans[k * TT + lane];
        float e[TT];
        #pragma unroll
        for (int j = 0; j < TT; ++j)
            e[j] = __expf(lds[lane * 65 + j]);

        float beta = end_t[lane];

        float em0[GRP], em1[GRP];
        int   mk0[GRP], mk1[GRP];

        auto LOADB = [&](float* eb, int* mb, int g) {
            const int sb = 511 - g * GRP;                // prefetch overrun stays >= 0
            #pragma unroll
            for (int k = 0; k < GRP; ++k) {
                eb[k] = embase[(size_t)(sb - k) * BB * TT];
                mb[k] = mkbase[(sb - k) * BB];
            }
        };
        auto STEPSB = [&](const float* eb, const int* mb) {
            #pragma unroll
            for (int k = 0; k < GRP; ++k) {
                const int par = (k & 1) * TT;
                float qa  = eb[k] + beta;
                float off = bl0(qa);
                float q   = __expf(qa - off);
                lds[par + lane] = q;
                float a0 = 0.f, a1 = 0.f, a2 = 0.f, a3 = 0.f;
                #pragma unroll
                for (int j = 0; j < 16; ++j) {
                    float4 qv = *(const float4*)&lds[par + j * 4];
                    a0 += qv.x * e[4 * j + 0];
                    a1 += qv.y * e[4 * j + 1];
                    a2 += qv.z * e[4 * j + 2];
                    a3 += qv.w * e[4 * j + 3];
                }
                float acc = (a0 + a1) + (a2 + a3);
                float nb  = off + __logf(acc);
                beta = mb[k] ? nb : beta;
            }
        };

        LOADB(em0, mk0, 0);
        LOADB(em1, mk1, 1);
        for (int gg = 0; gg < 32; gg += 2) {
            STEPSB(em0, mk0);
            LOADB(em0, mk0, gg + 2);
            STEPSB(em1, mk1);
            LOADB(em1, mk1, gg + 3);
        }
        beta_mid[(size_t)b * TT + lane] = beta;

    } else {
        // ---------------- numerator (tag-path score) ----------------
        const int b = bid - 2 * BB;
        float local = 0.f;
        int   mcnt  = 0;
        for (int s = lane; s < SS; s += 64) {
            int tag = tags[s * BB + b];
            int mk  = mask[s * BB + b];
            mcnt += mk;
            if (s == 0) {
                local += start_t[tag] + em[(size_t)b * TT + tag];
            } else if (mk) {
                int tp = tags[(s - 1) * BB + b];
                local += trans[tp * TT + tag] + em[(size_t)s * BB * TT + (size_t)b * TT + tag];
            }
        }
        #pragma unroll
        for (int d = 32; d > 0; d >>= 1) {
            local += __shfl_down(local, d, 64);
            mcnt  += __shfl_down(mcnt, d, 64);
        }
        if (lane == 0) {
            int last = tags[(mcnt - 1) * BB + b];
            num_ws[b] = local + end_t[last];
        }
    }
}

// per-batch denominator + llh (one wave per batch element)
__global__ __launch_bounds__(64) void crf_llh(
    const float* __restrict__ alpha_mid,
    const float* __restrict__ beta_mid,
    const float* __restrict__ num_ws,
    float* __restrict__ llh)
{
    const int b = blockIdx.x, lane = threadIdx.x;
    float v = alpha_mid[(size_t)b * TT + lane] + beta_mid[(size_t)b * TT + lane];
    float mx = v;
    #pragma unroll
    for (int d = 32; d > 0; d >>= 1) mx = fmaxf(mx, __shfl_xor(mx, d, 64));
    float s = __expf(v - mx);
    #pragma unroll
    for (int d = 32; d > 0; d >>= 1) s += __shfl_xor(s, d, 64);
    if (lane == 0) llh[b] = num_ws[b] - (mx + __logf(s));
}

__global__ __launch_bounds__(512) void crf_mean(const float* __restrict__ llh,
                                               float* __restrict__ out)
{
    const int t = threadIdx.x;
    float v = llh[t];
    #pragma unroll
    for (int d = 32; d > 0; d >>= 1) v += __shfl_down(v, d, 64);
    __shared__ float red[8];
    if ((t & 63) == 0) red[t >> 6] = v;
    __syncthreads();
    if (t == 0) {
        float s = 0.f;
        #pragma unroll
        for (int w = 0; w < 8; ++w) s += red[w];
        out[0] = s / (float)BB;
    }
}

extern "C" void kernel_launch(void* const* d_in, const int* in_sizes, int n_in,
                              void* d_out, int out_size, void* d_ws, size_t ws_size,
                              hipStream_t stream) {
    const float* em    = (const float*)d_in[0];
    const int*   tags  = (const int*)d_in[1];
    const int*   mask  = (const int*)d_in[2];
    const float* st    = (const float*)d_in[3];
    const float* en    = (const float*)d_in[4];
    const float* tr    = (const float*)d_in[5];

    float* ws        = (float*)d_ws;
    float* alpha_mid = ws;
    float* beta_mid  = ws + (size_t)BB * TT;
    float* num_ws    = ws + (size_t)2 * BB * TT;
    float* llh       = ws + (size_t)2 * BB * TT + BB;

    crf_chains<<<3 * BB, 64, 0, stream>>>(em, tags, mask, st, en, tr,
                                          alpha_mid, beta_mid, num_ws);
    crf_llh<<<BB, 64, 0, stream>>>(alpha_mid, beta_mid, num_ws, llh);
    crf_mean<<<1, 512, 0, stream>>>(llh, (float*)d_out);
}